// Round 6
// baseline (709.478 us; speedup 1.0000x reference)
//
#include <hip/hip_runtime.h>
#include <hip/hip_bf16.h>
#include <math.h>

// ---------------- problem constants ----------------
#define B_ROWS 1024
#define EMB    512
#define NCLS   100000
#define SCALE_ 64.0f
// margin = 0.5
#define COS_M 0.8775825618903728f
#define SIN_M 0.479425538604203f
#define TH_C  (-0.8775825618903728f)
#define MM_C  0.2397127693021015f

// ---------------- GEMM tiling ----------------
// BM=256 x BN=128: per-iter staging 24 KB for 32 MFMA/wave (vs 16 KB/16 at 128x128)
// -> CU-inbound bytes 1.6 GB -> 1.2 GB, W HBM duplication 8x -> 4x.
#define BM 256
#define BN 128
#define BK 32
#define NTILES 782   // ceil(100000/128)
#define KCHUNKS 16   // 512/32
// Grid (4, 782), x fastest: the 4 blocks sharing a W-tile get consecutive ids ->
// 4 DIFFERENT XCDs. Verified R3 vs R4/R5: cross-XCD duplication outruns same-XCD
// L2 sharing (synchronized same-line streams hot-spot L2 channels).

typedef __attribute__((ext_vector_type(8))) short bf16x8;   // 8 bf16 = 4 VGPRs
typedef __attribute__((ext_vector_type(4))) float f32x4;

typedef __attribute__((address_space(1))) const unsigned int GLP;
typedef __attribute__((address_space(3))) unsigned int LDP;

__device__ __forceinline__ float bf2f(short u) {
  unsigned int x = ((unsigned int)(unsigned short)u) << 16;
  return __builtin_bit_cast(float, x);
}
__device__ __forceinline__ short f2bf(float f) {   // RNE fp32 -> bf16
  unsigned int u = __builtin_bit_cast(unsigned int, f);
  u += 0x7FFF + ((u >> 16) & 1);
  return (short)(u >> 16);
}

// async global->LDS; lane i lands at (uniform base) + 16*i
__device__ __forceinline__ void load16(const void* g, void* l) {
  __builtin_amdgcn_global_load_lds((GLP*)g, (LDP*)l, 16, 0, 0);
}

// ---------------- fused: NT-GEMM + A/W norms + margin + softmax denominator ----------------
// All-in-one: per-block prologue probes dtype (bf16 vs fp32) and label width
// (int64 vs int32); A-row and W-row inverse norms are computed from the MFMA
// fragments already passing through registers (no separate norm pass).
__global__ __launch_bounds__(256, 2) void arc_gemm(
    const void* __restrict__ A, const void* __restrict__ W,
    const int* __restrict__ labels,
    float* __restrict__ row_sum, float* __restrict__ lablogit) {
  __shared__ short As[BM * BK];     // 16 KB, row-major [row][k], row stride 64 B
  __shared__ short Bs[BN * BK];     // 8 KB
  __shared__ int   sh_lab[BM];
  __shared__ float sh_inv[BM];      // A-row inverse norms (transposed via LDS)
  __shared__ float sh_sum[BM][2];
  __shared__ int   sh_flags[2];     // [0]=isbf16, [1]=labels-are-int64

  const int tid  = threadIdx.x;
  const int wave = tid >> 6;
  const int lane = tid & 63;
  const int wy = wave >> 1;         // 2x2 wave grid, each wave 128 rows x 64 cols
  const int wx = wave & 1;
  const int lr = lane & 15;
  const int lk = lane >> 4;
  const int mBase = blockIdx.x * BM;
  const int nBase = blockIdx.y * BN;

  // ---- prologue probes ----
  if (wave == 0) {
    // dtype probe: ssq of emb row 0 read AS bf16 (fp32 data -> inf/NaN whp)
    bf16x8 v = *(const bf16x8*)((const short*)A + lane * 8);
    float s = 0.f;
    #pragma unroll
    for (int j = 0; j < 8; ++j) { float f = bf2f(v[j]); s += f * f; }
    #pragma unroll
    for (int off = 1; off < 64; off <<= 1) s += __shfl_xor(s, off);
    if (lane == 0) sh_flags[0] = (s < 1e8f) ? 1 : 0;
  } else if (wave == 1) {
    // label width: int64 high words (odd ints) all zero. Indices <256: safe for both widths.
    int v = labels[2 * lane + 1] | labels[2 * (lane + 64) + 1];
    #pragma unroll
    for (int off = 1; off < 64; off <<= 1) v |= __shfl_xor(v, off);
    if (lane == 0) sh_flags[1] = (v == 0) ? 1 : 0;
  }
  __syncthreads();
  const int isbf16 = sh_flags[0];
  const int lab64  = sh_flags[1];
  {
    const int r = mBase + tid;            // tid < 256 == BM
    sh_lab[tid] = labels[lab64 ? (size_t)(2 * r) : (size_t)r];
  }

  const int srow  = lane >> 2;      // staging: 16 rows/instr, 4 lanes = one 64-B line
  const int sbyte = (lane & 3) * 16;

  f32x4 zero = {0.f, 0.f, 0.f, 0.f};
  f32x4 acc[8][4];
  #pragma unroll
  for (int i = 0; i < 8; ++i)
    #pragma unroll
    for (int j = 0; j < 4; ++j) acc[i][j] = zero;
  float ssqA[8] = {0.f, 0.f, 0.f, 0.f, 0.f, 0.f, 0.f, 0.f};
  float ssqB[4] = {0.f, 0.f, 0.f, 0.f};

  const char*  Ab = (const char*)A;   // bf16 row stride 1024 B
  const char*  Wb = (const char*)W;
  const float* Af = (const float*)A;  // fp32 row stride 512 floats
  const float* Wf = (const float*)W;

  for (int kc = 0; kc < KCHUNKS; ++kc) {
    __syncthreads();
    if (isbf16) {
      const size_t koff = (size_t)kc * 64 + sbyte;
      #pragma unroll
      for (int it = 0; it < 4; ++it) {                // A: 16 chunks of 16 rows
        const int c = wave + it * 4;
        const int ar = mBase + c * 16 + srow;         // always < 1024
        load16(Ab + (size_t)ar * 1024 + koff, (char*)As + (size_t)c * 1024);
      }
      #pragma unroll
      for (int it = 0; it < 2; ++it) {                // B: 8 chunks
        const int c = wave + it * 4;
        int br = nBase + c * 16 + srow;
        if (br >= NCLS) br = NCLS - 1;                // clamp; masked in epilogue
        load16(Wb + (size_t)br * 1024 + koff, (char*)Bs + (size_t)c * 1024);
      }
    } else {
      // fp32 path: float4 x2 loads, cvt RNE->bf16, ds_write 16B
      #pragma unroll
      for (int p = 0; p < 4; ++p) {                   // A: 1024 units of 8 elems
        const int u   = p * 256 + tid;
        const int row = u >> 2;
        const int seg = u & 3;
        const float* ga = Af + ((size_t)(mBase + row) * EMB + kc * 32 + seg * 8);
        f32x4 x = *(const f32x4*)ga;
        f32x4 y = *(const f32x4*)(ga + 4);
        bf16x8 tpack;
        #pragma unroll
        for (int j = 0; j < 4; ++j) { tpack[j] = f2bf(x[j]); tpack[j + 4] = f2bf(y[j]); }
        *(bf16x8*)(As + row * BK + seg * 8) = tpack;
      }
      #pragma unroll
      for (int p = 0; p < 2; ++p) {                   // B: 512 units
        const int u   = p * 256 + tid;
        const int row = u >> 2;
        const int seg = u & 3;
        int br = nBase + row;
        if (br >= NCLS) br = NCLS - 1;
        const float* gb = Wf + ((size_t)br * EMB + kc * 32 + seg * 8);
        f32x4 x = *(const f32x4*)gb;
        f32x4 y = *(const f32x4*)(gb + 4);
        bf16x8 tpack;
        #pragma unroll
        for (int j = 0; j < 4; ++j) { tpack[j] = f2bf(x[j]); tpack[j + 4] = f2bf(y[j]); }
        *(bf16x8*)(Bs + row * BK + seg * 8) = tpack;
      }
    }
    __syncthreads();
    bf16x8 af[8], bfr[4];
    #pragma unroll
    for (int mi = 0; mi < 8; ++mi) {
      af[mi] = *(const bf16x8*)(As + ((wy * 128 + mi * 16 + lr) * BK + lk * 8));
      #pragma unroll
      for (int j = 0; j < 8; ++j) { float f = bf2f(af[mi][j]); ssqA[mi] += f * f; }
    }
    #pragma unroll
    for (int ni = 0; ni < 4; ++ni) {
      bfr[ni] = *(const bf16x8*)(Bs + ((wx * 64 + ni * 16 + lr) * BK + lk * 8));
      #pragma unroll
      for (int j = 0; j < 8; ++j) { float f = bf2f(bfr[ni][j]); ssqB[ni] += f * f; }
    }
    #pragma unroll
    for (int mi = 0; mi < 8; ++mi)
      #pragma unroll
      for (int ni = 0; ni < 4; ++ni)
        acc[mi][ni] = __builtin_amdgcn_mfma_f32_16x16x32_bf16(af[mi], bfr[ni], acc[mi][ni], 0, 0, 0);
  }

  // ---- norm finish ----
  // W rows: lane-local; rinvB[ni] = inv-norm of W row (nBase + wx*64 + ni*16 + lr)
  float rinvB[4];
  #pragma unroll
  for (int ni = 0; ni < 4; ++ni) {
    float t = ssqB[ni];
    t += __shfl_xor(t, 16);
    t += __shfl_xor(t, 32);
    rinvB[ni] = 1.f / fmaxf(sqrtf(t), 1e-12f);
  }
  // A rows: computed keyed by lr, consumed keyed by lk*4+reg -> transpose via LDS
  #pragma unroll
  for (int mi = 0; mi < 8; ++mi) {
    float t = ssqA[mi];
    t += __shfl_xor(t, 16);
    t += __shfl_xor(t, 32);
    if (wx == 0 && lk == 0)
      sh_inv[wy * 128 + mi * 16 + lr] = 1.f / fmaxf(sqrtf(t), 1e-12f);
  }
  __syncthreads();

  // ---- epilogue ----
  #pragma unroll
  for (int mi = 0; mi < 8; ++mi) {
    #pragma unroll
    for (int reg = 0; reg < 4; ++reg) {
      const int lrow = wy * 128 + mi * 16 + lk * 4 + reg;  // C/D: row=(lane>>4)*4+reg
      const int grow = mBase + lrow;
      const float ie = sh_inv[lrow];
      const int lab = sh_lab[lrow];
      float s = 0.f;
      #pragma unroll
      for (int ni = 0; ni < 4; ++ni) {
        const int gcol = nBase + wx * 64 + ni * 16 + lr;   // C/D: col=lane&15
        if (gcol < NCLS) {
          const float cosv = acc[mi][ni][reg] * ie * rinvB[ni];
          float logit;
          if (gcol == lab) {
            const float sine = sqrtf(fmaxf(1.f - cosv * cosv, 0.f));
            float phi = cosv * COS_M - sine * SIN_M;
            phi = (cosv > TH_C) ? phi : (cosv - MM_C);
            logit = SCALE_ * phi;
            lablogit[grow] = logit;                        // unique writer grid-wide
          } else {
            logit = SCALE_ * cosv;
          }
          s += __expf(logit - SCALE_);                     // offset-64 softmax partial
        }
      }
      #pragma unroll
      for (int off = 1; off < 16; off <<= 1) s += __shfl_xor(s, off);
      if (lr == 0) sh_sum[lrow][wx] = s;
    }
  }
  __syncthreads();
  atomicAdd(&row_sum[mBase + tid], sh_sum[tid][0] + sh_sum[tid][1]);  // tid < 256 == BM
}

// ---------------- per-row loss -> mean (single block, deterministic) ----------------
__global__ void loss_kernel(const float* __restrict__ row_sum,
                            const float* __restrict__ lablogit,
                            float* __restrict__ out) {
  const int r = threadIdx.x;          // 1024 threads
  float loss = SCALE_ + logf(row_sum[r]) - lablogit[r];
  #pragma unroll
  for (int off = 1; off < 64; off <<= 1) loss += __shfl_xor(loss, off);
  __shared__ float rs[16];
  if ((r & 63) == 0) rs[r >> 6] = loss;
  __syncthreads();
  if (r == 0) {
    float t = 0.f;
    #pragma unroll
    for (int i = 0; i < 16; ++i) t += rs[i];
    out[0] = t * (1.0f / 1024.0f);    // reference output is float32
  }
}

// ---------------- launch ----------------
extern "C" void kernel_launch(void* const* d_in, const int* in_sizes, int n_in,
                              void* d_out, int out_size, void* d_ws, size_t ws_size,
                              hipStream_t stream) {
  const void* emb   = d_in[0];          // [1024][512]  bf16 or fp32 (auto-detected)
  const void* wgt   = d_in[1];          // [100000][512]
  const int* labels = (const int*)d_in[2];   // int32 or int64 (auto-detected)
  float* out = (float*)d_out;

  float* ws       = (float*)d_ws;
  float* row_sum  = ws;                 // 1024
  float* lablogit = ws + 1024;          // 1024

  hipMemsetAsync(row_sum, 0, B_ROWS * sizeof(float), stream);
  dim3 grid(B_ROWS / BM, NTILES);       // (4, 782), x fastest -> sharing blocks on different XCDs
  arc_gemm<<<grid, 256, 0, stream>>>(emb, wgt, labels, row_sum, lablogit);
  loss_kernel<<<1, 1024, 0, stream>>>(row_sum, lablogit, out);
}